// Round 7
// baseline (127.335 us; speedup 1.0000x reference)
//
#include <hip/hip_runtime.h>
#include <math.h>

#define B_    2
#define C_    64
#define N_    20000
#define K_    16
#define COUT_ 64
#define TN1   64
#define NB1   ((N_ + TN1 - 1) / TN1)   // 313
#define TN2   16
#define NB2   (N_ / TN2)               // 1250 (exact, no tail)

typedef unsigned int   u32;
typedef unsigned short u16;

static __device__ __forceinline__ u16 f2bf(float f) {
    union { float f; u32 u; } v; v.f = f;
    u32 r = (v.u + 0x7FFFu + ((v.u >> 16) & 1u)) >> 16;  // RNE
    return (u16)r;
}
static __device__ __forceinline__ float uasf(u32 u) {
    union { u32 u; float f; } v; v.u = u; return v.f;
}

// ---------------------------------------------------------------------------
// Stage 1: z = (W1-W2)x + b, y = W2 x  -> bf16 tables [b][n][64ch] (128 B
// rows), plus edge prep packed as uint2(indices, suppression).
// SCRATCH-PROOF: weights live in LDS [c][(wz,wy)] (per-lane float2 read,
// conflict-free); accumulators are 8 NAMED float4s. No per-thread arrays --
// rounds 3/4 proved LLVM demotes them to scratch (330 us, 564 MB writes).
// ---------------------------------------------------------------------------
__global__ __launch_bounds__(256)
void stage1(const float* __restrict__ x, const int* __restrict__ ei,
            const float* __restrict__ pos, const float* __restrict__ W,
            const float* __restrict__ bias,
            u16* __restrict__ zbuf, u16* __restrict__ ybuf,
            uint2* __restrict__ es) {
    __shared__ float xt[64][68];    // [c][n_local], rows 16B-aligned
    __shared__ float wc[64][130];   // [c][2*o+{0,1}] = (w1-w2, w2)

    const int bi   = blockIdx.x;
    const int b    = bi / NB1;
    const int n0   = (bi % NB1) * TN1;
    const int t    = threadIdx.x;
    const int lane = t & 63;        // = output channel o
    const int w    = t >> 6;

    // ---- stage weights (coalesced): 64o x 64c ----
    #pragma unroll
    for (int r = 0; r < 16; ++r) {
        int flat = r * 256 + t;
        int o = flat >> 6, c = flat & 63;
        float w1 = W[o * 128 + c];
        float w2 = W[o * 128 + 64 + c];
        wc[c][2 * o]     = w1 - w2;
        wc[c][2 * o + 1] = w2;
    }
    // ---- stage x tile [c][n] via float4 (coalesced) ----
    const float* xb = x + (size_t)b * C_ * N_;
    #pragma unroll
    for (int r = 0; r < 4; ++r) {
        int flat = r * 256 + t;
        int c = flat >> 4, ng = (flat & 15) * 4;
        int n = n0 + ng;
        float4 v;
        if (n + 3 < N_) {
            v = *(const float4*)&xb[c * N_ + n];
        } else {
            v.x = (n     < N_) ? xb[c * N_ + n    ] : 0.0f;
            v.y = (n + 1 < N_) ? xb[c * N_ + n + 1] : 0.0f;
            v.z = (n + 2 < N_) ? xb[c * N_ + n + 2] : 0.0f;
            v.w = (n + 3 < N_) ? xb[c * N_ + n + 3] : 0.0f;
        }
        *(float4*)&xt[c][ng] = v;
    }
    const float bo = bias[lane];
    __syncthreads();

    // ---- wave computes 16 nodes, all accumulators NAMED float4 ----
    const int nb = w * 16;
    float4 z0 = {bo,bo,bo,bo}, z1 = z0, z2 = z0, z3 = z0;
    float4 y0 = {0,0,0,0},     y1 = y0, y2 = y0, y3 = y0;

#define FMA4(ZR, YR, XV) \
    ZR.x = fmaf(wv.x, XV.x, ZR.x);  YR.x = fmaf(wv.y, XV.x, YR.x); \
    ZR.y = fmaf(wv.x, XV.y, ZR.y);  YR.y = fmaf(wv.y, XV.y, YR.y); \
    ZR.z = fmaf(wv.x, XV.z, ZR.z);  YR.z = fmaf(wv.y, XV.z, YR.z); \
    ZR.w = fmaf(wv.x, XV.w, ZR.w);  YR.w = fmaf(wv.y, XV.w, YR.w);

    #pragma unroll 2
    for (int c = 0; c < 64; ++c) {
        float2 wv = *(const float2*)&wc[c][2 * lane];   // conflict-free
        float4 xa = *(const float4*)&xt[c][nb];         // uniform broadcasts
        float4 xv1 = *(const float4*)&xt[c][nb + 4];
        float4 xv2 = *(const float4*)&xt[c][nb + 8];
        float4 xv3 = *(const float4*)&xt[c][nb + 12];
        FMA4(z0, y0, xa)
        FMA4(z1, y1, xv1)
        FMA4(z2, y2, xv2)
        FMA4(z3, y3, xv3)
    }
#undef FMA4

    {
        const size_t rowb = (size_t)b * N_;
        auto st = [&](int i, float zv, float yv) {
            int n = n0 + nb + i;
            if (n < N_) {
                size_t off = (rowb + n) * 64 + lane;    // 128 B coalesced
                zbuf[off] = f2bf(zv);
                ybuf[off] = f2bf(yv);
            }
        };
        st(0,  z0.x, y0.x); st(1,  z0.y, y0.y); st(2,  z0.z, y0.z); st(3,  z0.w, y0.w);
        st(4,  z1.x, y1.x); st(5,  z1.y, y1.y); st(6,  z1.z, y1.z); st(7,  z1.w, y1.w);
        st(8,  z2.x, y2.x); st(9,  z2.y, y2.y); st(10, z2.z, y2.z); st(11, z2.w, y2.w);
        st(12, z3.x, y3.x); st(13, z3.y, y3.y); st(14, z3.z, y3.z); st(15, z3.w, y3.w);
    }

    // ---- edge prep: pack (i0,i1) + fp32 suppression into one uint2 ----
    const int*   e0 = ei + (size_t)b * N_ * K_;
    const int*   e1 = ei + ((size_t)B_ + b) * N_ * K_;
    const float* pb = pos + (size_t)b * 3 * N_;
    uint2* esb = es + (size_t)b * N_ * K_;
    #pragma unroll
    for (int i = 0; i < 4; ++i) {
        int idx = n0 * K_ + i * 256 + t;     // coalesced
        if (idx < N_ * K_) {
            int i0 = e0[idx], i1 = e1[idx];
            float dx = pb[i0]          - pb[i1];
            float dy = pb[N_ + i0]     - pb[N_ + i1];
            float dz = pb[2 * N_ + i0] - pb[2 * N_ + i1];
            float dis = sqrtf(dx * dx + dy * dy + dz * dz);
            float s = 2.0f / (1.0f + __expf(dis));      // 2*sigmoid(-dis)
            esb[idx] = make_uint2((u32)i0 | ((u32)i1 << 16), __float_as_uint(s));
        }
    }
}

// ---------------------------------------------------------------------------
// Stage 2: out[b][o][n] = max_k relu(z[i1][o] + y[i0][o]) * s_k.
// ONE WAVE PER NODE: lane = (k = lane>>2, chunk-pair c2 = lane&3). Each lane
// issues 4 independent 16 B gathers (its k's z/y half-rows) -> a single
// vmcnt drain per node instead of round 6's 8-deep serial chain. Max over
// the 16 k's is a 4-round shfl_xor reduce (strides 4/8/16/32) in-register.
// 1024-thread blocks (16 nodes), 2500 blocks.
// ---------------------------------------------------------------------------
__global__ __launch_bounds__(1024)
void stage2(const uint2* __restrict__ es,
            const u16* __restrict__ zbuf, const u16* __restrict__ ybuf,
            float* __restrict__ out) {
    __shared__ float tile[TN2][68];      // row = 272 B (16B-aligned), 2-way banks

    const int bi   = blockIdx.x;
    const int b    = bi / NB2;
    const int n0   = (bi % NB2) * TN2;
    const int t    = threadIdx.x;
    const int w    = t >> 6;             // wave = node 0..15
    const int lane = t & 63;
    const int k    = lane >> 2;          // edge 0..15
    const int c2   = lane & 3;           // 32 B chunk-pair = 16 channels

    const int n = n0 + w;
    uint2 e = es[(size_t)b * N_ * K_ + (size_t)n * K_ + k];  // 128 B/wave, L2-hot
    const int   i0 = (int)(e.x & 0xFFFFu);
    const int   i1 = (int)(e.x >> 16);
    const float s  = uasf(e.y);

    const u16* zr = zbuf + (size_t)b * N_ * 64 + ((size_t)i1 << 6) + c2 * 16;
    const u16* yr = ybuf + (size_t)b * N_ * 64 + ((size_t)i0 << 6) + c2 * 16;
    uint4 z4a = *(const uint4*)zr;           // 4 independent b128 gathers,
    uint4 z4b = *(const uint4*)(zr + 8);     // one waitcnt drain
    uint4 y4a = *(const uint4*)yr;
    uint4 y4b = *(const uint4*)(yr + 8);

#define MKV(ZW, YW, VLO, VHI) { \
    float zl = uasf((ZW) << 16), zh = uasf((ZW) & 0xFFFF0000u); \
    float yl = uasf((YW) << 16), yh = uasf((YW) & 0xFFFF0000u); \
    VLO = fmaxf(zl + yl, 0.0f) * s; \
    VHI = fmaxf(zh + yh, 0.0f) * s; }

    float4 va, vb, vc, vd;                   // 16 channels of this (n, k)
    MKV(z4a.x, y4a.x, va.x, va.y)
    MKV(z4a.y, y4a.y, va.z, va.w)
    MKV(z4a.z, y4a.z, vb.x, vb.y)
    MKV(z4a.w, y4a.w, vb.z, vb.w)
    MKV(z4b.x, y4b.x, vc.x, vc.y)
    MKV(z4b.y, y4b.y, vc.z, vc.w)
    MKV(z4b.z, y4b.z, vd.x, vd.y)
    MKV(z4b.w, y4b.w, vd.z, vd.w)
#undef MKV

    // ---- max over 16 k's: xor-reduce lane bits 2..5 (c2 classes intact) ----
#define R4(V, ST) \
    V.x = fmaxf(V.x, __shfl_xor(V.x, ST)); \
    V.y = fmaxf(V.y, __shfl_xor(V.y, ST)); \
    V.z = fmaxf(V.z, __shfl_xor(V.z, ST)); \
    V.w = fmaxf(V.w, __shfl_xor(V.w, ST));
    R4(va, 4)  R4(vb, 4)  R4(vc, 4)  R4(vd, 4)
    R4(va, 8)  R4(vb, 8)  R4(vc, 8)  R4(vd, 8)
    R4(va, 16) R4(vb, 16) R4(vc, 16) R4(vd, 16)
    R4(va, 32) R4(vb, 32) R4(vc, 32) R4(vd, 32)
#undef R4

    if (k == 0) {                        // lanes 0..3 hold ch c2*16..c2*16+15
        int cb = c2 * 16;
        *(float4*)&tile[w][cb]      = va;
        *(float4*)&tile[w][cb + 4]  = vb;
        *(float4*)&tile[w][cb + 8]  = vc;
        *(float4*)&tile[w][cb + 12] = vd;
    }
    __syncthreads();

    // ---- coalesced writeback: 64 o x 16 n, 64 B per o-row ----
    {
        int o  = t >> 4;
        int n2 = t & 15;
        out[((size_t)b * COUT_ + o) * N_ + n0 + n2] = tile[n2][o];
    }
}

// ---------------------------------------------------------------------------
extern "C" void kernel_launch(void* const* d_in, const int* in_sizes, int n_in,
                              void* d_out, int out_size, void* d_ws, size_t ws_size,
                              hipStream_t stream) {
    const float* x    = (const float*)d_in[0];   // [B, C, N, 1]
    const int*   ei   = (const int*)  d_in[1];   // [2, B, N, K]
    const float* pos  = (const float*)d_in[2];   // [B, 3, N, 1]
    const float* W    = (const float*)d_in[3];   // [COUT, 2C]
    const float* bias = (const float*)d_in[4];   // [COUT]
    float*       out  = (float*)d_out;           // [B, COUT, N, 1]

    const size_t tabElems = (size_t)B_ * N_ * 64;            // 2.56M u16
    u16*   zbuf = (u16*)d_ws;                                // 5.12 MB
    u16*   ybuf = zbuf + tabElems;                           // 5.12 MB
    uint2* es   = (uint2*)(ybuf + tabElems);                 // 5.12 MB, 8B-aligned

    hipLaunchKernelGGL(stage1, dim3(B_ * NB1), dim3(256), 0, stream,
                       x, ei, pos, W, bias, zbuf, ybuf, es);
    hipLaunchKernelGGL(stage2, dim3(B_ * NB2), dim3(1024), 0, stream,
                       es, zbuf, ybuf, out);
}

// Round 8
// 109.489 us; speedup vs baseline: 1.1630x; 1.1630x over previous
//
#include <hip/hip_runtime.h>
#include <math.h>

#define B_    2
#define C_    64
#define N_    20000
#define K_    16
#define COUT_ 64
#define TN1   64
#define NB1   ((N_ + TN1 - 1) / TN1)   // 313
#define TN2   16
#define NB2   (N_ / TN2)               // 1250 (exact, no tail)

typedef unsigned int   u32;
typedef unsigned short u16;

static __device__ __forceinline__ u16 f2bf(float f) {
    union { float f; u32 u; } v; v.f = f;
    u32 r = (v.u + 0x7FFFu + ((v.u >> 16) & 1u)) >> 16;  // RNE
    return (u16)r;
}
static __device__ __forceinline__ float uasf(u32 u) {
    union { u32 u; float f; } v; v.u = u; return v.f;
}

// ---------------------------------------------------------------------------
// Stage 1: PURE per-node GEMM. z = (W1-W2)x + b, y = W2 x -> bf16 tables
// [b][n][64ch] (128 B rows). Edge prep moved to stage 2 (saves the es
// buffer's 10.24 MB round trip).
// SCRATCH-PROOF: weights in LDS [c][(wz,wy)]; accumulators are 8 NAMED
// float4s. No per-thread arrays (rounds 3/4: LLVM demotes them to scratch).
// ---------------------------------------------------------------------------
__global__ __launch_bounds__(256)
void stage1(const float* __restrict__ x, const float* __restrict__ W,
            const float* __restrict__ bias,
            u16* __restrict__ zbuf, u16* __restrict__ ybuf) {
    __shared__ float xt[64][68];    // [c][n_local], rows 16B-aligned
    __shared__ float wc[64][130];   // [c][2*o+{0,1}] = (w1-w2, w2)

    const int bi   = blockIdx.x;
    const int b    = bi / NB1;
    const int n0   = (bi % NB1) * TN1;
    const int t    = threadIdx.x;
    const int lane = t & 63;        // = output channel o
    const int w    = t >> 6;

    // ---- stage weights (coalesced): 64o x 64c ----
    #pragma unroll
    for (int r = 0; r < 16; ++r) {
        int flat = r * 256 + t;
        int o = flat >> 6, c = flat & 63;
        float w1 = W[o * 128 + c];
        float w2 = W[o * 128 + 64 + c];
        wc[c][2 * o]     = w1 - w2;
        wc[c][2 * o + 1] = w2;
    }
    // ---- stage x tile [c][n] via float4 (coalesced) ----
    const float* xb = x + (size_t)b * C_ * N_;
    #pragma unroll
    for (int r = 0; r < 4; ++r) {
        int flat = r * 256 + t;
        int c = flat >> 4, ng = (flat & 15) * 4;
        int n = n0 + ng;
        float4 v;
        if (n + 3 < N_) {
            v = *(const float4*)&xb[c * N_ + n];
        } else {
            v.x = (n     < N_) ? xb[c * N_ + n    ] : 0.0f;
            v.y = (n + 1 < N_) ? xb[c * N_ + n + 1] : 0.0f;
            v.z = (n + 2 < N_) ? xb[c * N_ + n + 2] : 0.0f;
            v.w = (n + 3 < N_) ? xb[c * N_ + n + 3] : 0.0f;
        }
        *(float4*)&xt[c][ng] = v;
    }
    const float bo = bias[lane];
    __syncthreads();

    // ---- wave computes 16 nodes, all accumulators NAMED float4 ----
    const int nb = w * 16;
    float4 z0 = {bo,bo,bo,bo}, z1 = z0, z2 = z0, z3 = z0;
    float4 y0 = {0,0,0,0},     y1 = y0, y2 = y0, y3 = y0;

#define FMA4(ZR, YR, XV) \
    ZR.x = fmaf(wv.x, XV.x, ZR.x);  YR.x = fmaf(wv.y, XV.x, YR.x); \
    ZR.y = fmaf(wv.x, XV.y, ZR.y);  YR.y = fmaf(wv.y, XV.y, YR.y); \
    ZR.z = fmaf(wv.x, XV.z, ZR.z);  YR.z = fmaf(wv.y, XV.z, YR.z); \
    ZR.w = fmaf(wv.x, XV.w, ZR.w);  YR.w = fmaf(wv.y, XV.w, YR.w);

    #pragma unroll 2
    for (int c = 0; c < 64; ++c) {
        float2 wv = *(const float2*)&wc[c][2 * lane];   // conflict-free
        float4 xa = *(const float4*)&xt[c][nb];         // uniform broadcasts
        float4 xv1 = *(const float4*)&xt[c][nb + 4];
        float4 xv2 = *(const float4*)&xt[c][nb + 8];
        float4 xv3 = *(const float4*)&xt[c][nb + 12];
        FMA4(z0, y0, xa)
        FMA4(z1, y1, xv1)
        FMA4(z2, y2, xv2)
        FMA4(z3, y3, xv3)
    }
#undef FMA4

    {
        const size_t rowb = (size_t)b * N_;
        auto st = [&](int i, float zv, float yv) {
            int n = n0 + nb + i;
            if (n < N_) {
                size_t off = (rowb + n) * 64 + lane;    // 128 B coalesced
                zbuf[off] = f2bf(zv);
                ybuf[off] = f2bf(yv);
            }
        };
        st(0,  z0.x, y0.x); st(1,  z0.y, y0.y); st(2,  z0.z, y0.z); st(3,  z0.w, y0.w);
        st(4,  z1.x, y1.x); st(5,  z1.y, y1.y); st(6,  z1.z, y1.z); st(7,  z1.w, y1.w);
        st(8,  z2.x, y2.x); st(9,  z2.y, y2.y); st(10, z2.z, y2.z); st(11, z2.w, y2.w);
        st(12, z3.x, y3.x); st(13, z3.y, y3.y); st(14, z3.z, y3.z); st(15, z3.w, y3.w);
    }
}

// ---------------------------------------------------------------------------
// Stage 2 (round-6 proven core + fused edge prep).
// Phase A: 1 edge/thread (256 edges = TN2*K): coalesced e0/e1 loads, 6 pos
//          gathers (pos = 240 KB, L2-hot), s = 2*sigmoid(-dis) -> LDS.
// Phase B: lane = (node nl = t>>4, k-parity kh, 16B chunk cq); 8 k's fully
//          unrolled (16 b128 gathers in flight), shfl_xor(8) parity merge.
// out stores nontemporal: don't evict the z/y tables.
// ---------------------------------------------------------------------------
__global__ __launch_bounds__(256)
void stage2(const int* __restrict__ ei, const float* __restrict__ pos,
            const u16* __restrict__ zbuf, const u16* __restrict__ ybuf,
            float* __restrict__ out) {
    __shared__ uint2 esl[TN2][17];       // pad 17 -> low-conflict reads
    __shared__ float tile[TN2][66];      // [n_local][o]

    const int bi   = blockIdx.x;
    const int b    = bi / NB2;
    const int n0   = (bi % NB2) * TN2;
    const int t    = threadIdx.x;
    const int nl   = t >> 4;             // node 0..15
    const int kh   = (t >> 3) & 1;       // k parity 0/1
    const int cq   = t & 7;              // 16B chunk = 8 channels

    // ---- Phase A: edge prep for this tile's 256 edges (1/thread) ----
    {
        const int    idx = n0 * K_ + t;                      // coalesced
        const int*   e0  = ei + (size_t)b * N_ * K_;
        const int*   e1  = ei + ((size_t)B_ + b) * N_ * K_;
        const float* pb  = pos + (size_t)b * 3 * N_;
        int i0 = e0[idx], i1 = e1[idx];
        float dx = pb[i0]          - pb[i1];
        float dy = pb[N_ + i0]     - pb[N_ + i1];
        float dz = pb[2 * N_ + i0] - pb[2 * N_ + i1];
        float dis = sqrtf(dx * dx + dy * dy + dz * dz);
        float s = 2.0f / (1.0f + __expf(dis));               // 2*sigmoid(-dis)
        esl[t >> 4][t & 15] = make_uint2((u32)i0 | ((u32)i1 << 16),
                                         __float_as_uint(s));
    }
    __syncthreads();

    const u16* zb = zbuf + (size_t)b * N_ * 64;
    const u16* yb = ybuf + (size_t)b * N_ * 64;

    float4 ma = {0,0,0,0}, mb = {0,0,0,0};   // 8 channel maxima (named)

#define COMB(ZW, YW, MLO, MHI) { \
    float zl = uasf((ZW) << 16), zh = uasf((ZW) & 0xFFFF0000u); \
    float yl = uasf((YW) << 16), yh = uasf((YW) & 0xFFFF0000u); \
    MLO = fmaxf(MLO, fmaxf(zl + yl, 0.0f) * s); \
    MHI = fmaxf(MHI, fmaxf(zh + yh, 0.0f) * s); }

    #pragma unroll
    for (int i = 0; i < 8; ++i) {
        int   k = 2 * i + kh;
        uint2 e = esl[nl][k];            // 8-lane broadcast
        int   i0 = (int)(e.x & 0xFFFFu);
        int   i1 = (int)(e.x >> 16);
        float s  = uasf(e.y);
        uint4 z4 = *((const uint4*)(zb + ((size_t)i1 << 6)) + cq);  // 16 B
        uint4 y4 = *((const uint4*)(yb + ((size_t)i0 << 6)) + cq);
        COMB(z4.x, y4.x, ma.x, ma.y)
        COMB(z4.y, y4.y, ma.z, ma.w)
        COMB(z4.z, y4.z, mb.x, mb.y)
        COMB(z4.w, y4.w, mb.z, mb.w)
    }
#undef COMB

    // ---- merge the two k-parities (lane ^ 8 flips kh only) ----
    ma.x = fmaxf(ma.x, __shfl_xor(ma.x, 8));
    ma.y = fmaxf(ma.y, __shfl_xor(ma.y, 8));
    ma.z = fmaxf(ma.z, __shfl_xor(ma.z, 8));
    ma.w = fmaxf(ma.w, __shfl_xor(ma.w, 8));
    mb.x = fmaxf(mb.x, __shfl_xor(mb.x, 8));
    mb.y = fmaxf(mb.y, __shfl_xor(mb.y, 8));
    mb.z = fmaxf(mb.z, __shfl_xor(mb.z, 8));
    mb.w = fmaxf(mb.w, __shfl_xor(mb.w, 8));

    if (kh == 0) {
        int cb = cq * 8;
        *(float2*)&tile[nl][cb]     = make_float2(ma.x, ma.y);
        *(float2*)&tile[nl][cb + 2] = make_float2(ma.z, ma.w);
        *(float2*)&tile[nl][cb + 4] = make_float2(mb.x, mb.y);
        *(float2*)&tile[nl][cb + 6] = make_float2(mb.z, mb.w);
    }
    __syncthreads();

    // ---- coalesced writeback: 64 o x 16 n (nontemporal: keep tables hot) ----
    #pragma unroll
    for (int r = 0; r < 4; ++r) {
        int flat = r * 256 + t;
        int o = flat >> 4, n2 = flat & 15;
        __builtin_nontemporal_store(tile[n2][o],
            &out[((size_t)b * COUT_ + o) * N_ + n0 + n2]);
    }
}

// ---------------------------------------------------------------------------
extern "C" void kernel_launch(void* const* d_in, const int* in_sizes, int n_in,
                              void* d_out, int out_size, void* d_ws, size_t ws_size,
                              hipStream_t stream) {
    const float* x    = (const float*)d_in[0];   // [B, C, N, 1]
    const int*   ei   = (const int*)  d_in[1];   // [2, B, N, K]
    const float* pos  = (const float*)d_in[2];   // [B, 3, N, 1]
    const float* W    = (const float*)d_in[3];   // [COUT, 2C]
    const float* bias = (const float*)d_in[4];   // [COUT]
    float*       out  = (float*)d_out;           // [B, COUT, N, 1]

    const size_t tabElems = (size_t)B_ * N_ * 64;            // 2.56M u16
    u16* zbuf = (u16*)d_ws;                                  // 5.12 MB
    u16* ybuf = zbuf + tabElems;                             // 5.12 MB

    hipLaunchKernelGGL(stage1, dim3(B_ * NB1), dim3(256), 0, stream,
                       x, W, bias, zbuf, ybuf);
    hipLaunchKernelGGL(stage2, dim3(B_ * NB2), dim3(256), 0, stream,
                       ei, pos, zbuf, ybuf, out);
}